// Round 1
// baseline (2202.726 us; speedup 1.0000x reference)
//
#include <hip/hip_runtime.h>

// Problem constants
#define EE 8
#define BB 1024
#define DD 8192
#define HH 512
#define ZZ 128

// GEMM tiling: 128x64 tile, K-step 16, 256 threads, 8x4 per-thread micro-tile.
constexpr int BM = 128;
constexpr int BN = 64;
constexpr int BK = 16;

__device__ __forceinline__ float4 ld4(const float* p) { return *(const float4*)p; }

// ---------------------------------------------------------------------------
// Generic fp32 GEMM: Y[e] = act(A[e or shared] @ W[e] + bias[e])
// A: [M,K] (shared) or [E,M,K]; W: [E,K,N]; bias: [E,N]; Y: [E,M,N]
// ---------------------------------------------------------------------------
template <bool APE, bool RELU>
__global__ __launch_bounds__(256) void gemm_k(const float* __restrict__ A,
                                              const float* __restrict__ W,
                                              const float* __restrict__ bias,
                                              float* __restrict__ Y,
                                              int M, int N, int K) {
  const int e = blockIdx.z;
  const int m0 = blockIdx.y * BM;
  const int n0 = blockIdx.x * BN;
  const float* Ae = APE ? A + (size_t)e * M * K : A;
  const float* We = W + (size_t)e * K * N;
  const float* be = bias + (size_t)e * N;
  float* Ye = Y + (size_t)e * M * N;

  __shared__ float As[BK][BM + 4];
  __shared__ float Bs[BK][BN + 4];

  const int tid = threadIdx.x;
  const int tx = tid & 15;       // 0..15 -> 4 cols each
  const int ty = tid >> 4;       // 0..15 -> 8 rows each
  const int ar = tid >> 1;       // A stage: row 0..127
  const int ak = (tid & 1) * 8;  // A stage: k offset 0 or 8
  const int bk = tid >> 4;       // B stage: k row 0..15
  const int bn = (tid & 15) * 4; // B stage: col offset

  float acc[8][4] = {};

  for (int k0 = 0; k0 < K; k0 += BK) {
    // Stage A tile (128 rows x 16 k), 8 floats/thread
    {
      const float* ap = Ae + (size_t)(m0 + ar) * K + k0 + ak;
      float av[8];
      *(float4*)&av[0] = ld4(ap);
      *(float4*)&av[4] = ld4(ap + 4);
#pragma unroll
      for (int j = 0; j < 8; ++j) As[ak + j][ar] = av[j];
    }
    // Stage B tile (16 k x 64 cols), 4 floats/thread
    {
      const float* wp = We + (size_t)(k0 + bk) * N + n0 + bn;
      *(float4*)&Bs[bk][bn] = ld4(wp);
    }
    __syncthreads();

#pragma unroll
    for (int k = 0; k < BK; ++k) {
      float a[8], b[4];
      *(float4*)&a[0] = *(const float4*)&As[k][ty * 8];
      *(float4*)&a[4] = *(const float4*)&As[k][ty * 8 + 4];
      *(float4*)&b[0] = *(const float4*)&Bs[k][tx * 4];
#pragma unroll
      for (int i = 0; i < 8; ++i)
#pragma unroll
        for (int j = 0; j < 4; ++j) acc[i][j] = fmaf(a[i], b[j], acc[i][j]);
    }
    __syncthreads();
  }

  float bb4[4];
  *(float4*)&bb4[0] = ld4(&be[n0 + tx * 4]);
#pragma unroll
  for (int i = 0; i < 8; ++i) {
    const int row = m0 + ty * 8 + i;
    float o[4];
#pragma unroll
    for (int j = 0; j < 4; ++j) {
      float v = acc[i][j] + bb4[j];
      if (RELU) v = fmaxf(v, 0.0f);
      o[j] = v;
    }
    *(float4*)&Ye[(size_t)row * N + n0 + tx * 4] = *(float4*)&o[0];
  }
}

// ---------------------------------------------------------------------------
// dec3 + fused loss: computes xhat tile, accumulates sum((xhat - xf)^2) over
// the block's 64 cols into partials[e][row][nblk]. xhat is NOT stored.
// ---------------------------------------------------------------------------
__global__ __launch_bounds__(256) void gemm_loss_k(const float* __restrict__ A,
                                                   const float* __restrict__ W,
                                                   const float* __restrict__ bias,
                                                   const float* __restrict__ xf,
                                                   float* __restrict__ partials,
                                                   int M, int N, int K, int NBLK) {
  const int e = blockIdx.z;
  const int m0 = blockIdx.y * BM;
  const int n0 = blockIdx.x * BN;
  const float* Ae = A + (size_t)e * M * K;
  const float* We = W + (size_t)e * K * N;
  const float* be = bias + (size_t)e * N;

  __shared__ float As[BK][BM + 4];
  __shared__ float Bs[BK][BN + 4];

  const int tid = threadIdx.x;
  const int tx = tid & 15;
  const int ty = tid >> 4;
  const int ar = tid >> 1;
  const int ak = (tid & 1) * 8;
  const int bk = tid >> 4;
  const int bn = (tid & 15) * 4;

  float acc[8][4] = {};

  for (int k0 = 0; k0 < K; k0 += BK) {
    {
      const float* ap = Ae + (size_t)(m0 + ar) * K + k0 + ak;
      float av[8];
      *(float4*)&av[0] = ld4(ap);
      *(float4*)&av[4] = ld4(ap + 4);
#pragma unroll
      for (int j = 0; j < 8; ++j) As[ak + j][ar] = av[j];
    }
    {
      const float* wp = We + (size_t)(k0 + bk) * N + n0 + bn;
      *(float4*)&Bs[bk][bn] = ld4(wp);
    }
    __syncthreads();

#pragma unroll
    for (int k = 0; k < BK; ++k) {
      float a[8], b[4];
      *(float4*)&a[0] = *(const float4*)&As[k][ty * 8];
      *(float4*)&a[4] = *(const float4*)&As[k][ty * 8 + 4];
      *(float4*)&b[0] = *(const float4*)&Bs[k][tx * 4];
#pragma unroll
      for (int i = 0; i < 8; ++i)
#pragma unroll
        for (int j = 0; j < 4; ++j) acc[i][j] = fmaf(a[i], b[j], acc[i][j]);
    }
    __syncthreads();
  }

  float bb4[4];
  *(float4*)&bb4[0] = ld4(&be[n0 + tx * 4]);
  float rs[8];
#pragma unroll
  for (int i = 0; i < 8; ++i) {
    const int row = m0 + ty * 8 + i;
    float xv[4];
    *(float4*)&xv[0] = ld4(&xf[(size_t)row * N + n0 + tx * 4]);
    float s = 0.0f;
#pragma unroll
    for (int j = 0; j < 4; ++j) {
      const float d = acc[i][j] + bb4[j] - xv[j];
      s = fmaf(d, d, s);
    }
    rs[i] = s;
  }
  // Reduce across the 16 tx lanes (consecutive lanes within a wave)
#pragma unroll
  for (int off = 1; off < 16; off <<= 1) {
#pragma unroll
    for (int i = 0; i < 8; ++i) rs[i] += __shfl_xor(rs[i], off);
  }
  if (tx == 0) {
#pragma unroll
    for (int i = 0; i < 8; ++i) {
      const int row = m0 + ty * 8 + i;
      partials[((size_t)e * BB + row) * NBLK + blockIdx.x] = rs[i];
    }
  }
}

// ---------------------------------------------------------------------------
// Gathered GEMM for the selected-expert xhat recompute.
// rows come from lists[e*BB + ...]; writes directly into d_out xhat region.
// ---------------------------------------------------------------------------
__global__ __launch_bounds__(256) void gemm_gather_k(const float* __restrict__ A,
                                                     const float* __restrict__ W,
                                                     const float* __restrict__ bias,
                                                     const int* __restrict__ counts,
                                                     const int* __restrict__ lists,
                                                     float* __restrict__ out,
                                                     int N, int K) {
  const int e = blockIdx.z;
  const int cnt = counts[e];
  const int m0 = blockIdx.y * BM;
  if (m0 >= cnt) return;
  const int n0 = blockIdx.x * BN;
  const float* Ae = A + (size_t)e * BB * K;
  const float* We = W + (size_t)e * K * N;
  const float* be = bias + (size_t)e * N;

  __shared__ float As[BK][BM + 4];
  __shared__ float Bs[BK][BN + 4];
  __shared__ int rows_s[BM];

  const int tid = threadIdx.x;
  const int tx = tid & 15;
  const int ty = tid >> 4;
  const int ar = tid >> 1;
  const int ak = (tid & 1) * 8;
  const int bk = tid >> 4;
  const int bn = (tid & 15) * 4;

  if (tid < BM) rows_s[tid] = (m0 + tid < cnt) ? lists[e * BB + m0 + tid] : -1;
  __syncthreads();

  float acc[8][4] = {};
  const int rb = rows_s[ar];

  for (int k0 = 0; k0 < K; k0 += BK) {
    {
      float av[8];
      if (rb >= 0) {
        const float* ap = Ae + (size_t)rb * K + k0 + ak;
        *(float4*)&av[0] = ld4(ap);
        *(float4*)&av[4] = ld4(ap + 4);
      } else {
#pragma unroll
        for (int j = 0; j < 8; ++j) av[j] = 0.0f;
      }
#pragma unroll
      for (int j = 0; j < 8; ++j) As[ak + j][ar] = av[j];
    }
    {
      const float* wp = We + (size_t)(k0 + bk) * N + n0 + bn;
      *(float4*)&Bs[bk][bn] = ld4(wp);
    }
    __syncthreads();

#pragma unroll
    for (int k = 0; k < BK; ++k) {
      float a[8], b[4];
      *(float4*)&a[0] = *(const float4*)&As[k][ty * 8];
      *(float4*)&a[4] = *(const float4*)&As[k][ty * 8 + 4];
      *(float4*)&b[0] = *(const float4*)&Bs[k][tx * 4];
#pragma unroll
      for (int i = 0; i < 8; ++i)
#pragma unroll
        for (int j = 0; j < 4; ++j) acc[i][j] = fmaf(a[i], b[j], acc[i][j]);
    }
    __syncthreads();
  }

  float bb4[4];
  *(float4*)&bb4[0] = ld4(&be[n0 + tx * 4]);
#pragma unroll
  for (int i = 0; i < 8; ++i) {
    const int rout = rows_s[ty * 8 + i];
    if (rout >= 0) {
      float o[4];
#pragma unroll
      for (int j = 0; j < 4; ++j) o[j] = acc[i][j] + bb4[j];
      *(float4*)&out[(size_t)rout * N + n0 + tx * 4] = *(float4*)&o[0];
    }
  }
}

// ---------------------------------------------------------------------------
// Small kernels
// ---------------------------------------------------------------------------
__global__ void z_k(const float* __restrict__ mu, const float* __restrict__ lv,
                    const float* __restrict__ eps, float* __restrict__ z) {
  const int t = blockIdx.x * blockDim.x + threadIdx.x;  // E*B*Z threads
  z[t] = fmaf(__expf(0.5f * lv[t]) == 0.0f ? 0.0f : expf(0.5f * lv[t]), eps[t], mu[t]);
}

__global__ void loss_reduce_k(const float* __restrict__ partials,
                              float* __restrict__ losses, int NBLK) {
  const int id = blockIdx.x * blockDim.x + threadIdx.x;  // E*B threads
  const float* p = partials + (size_t)id * NBLK;
  float s = 0.0f;
  for (int j = 0; j < NBLK; ++j) s += p[j];
  losses[id] = s;
}

__global__ void argmin_k(const float* __restrict__ losses, int* __restrict__ idx,
                         float* __restrict__ out_ix) {
  const int b = blockIdx.x * blockDim.x + threadIdx.x;  // B threads
  float best = losses[b];
  int bi = 0;
#pragma unroll
  for (int e = 1; e < EE; ++e) {
    const float v = losses[e * BB + b];
    if (v < best) { best = v; bi = e; }
  }
  idx[b] = bi;
  out_ix[b] = (float)bi;
}

__global__ void select_k(const float* __restrict__ mu, const float* __restrict__ lv,
                         const int* __restrict__ idx, float* __restrict__ out_mu,
                         float* __restrict__ out_lv) {
  const int t = blockIdx.x * blockDim.x + threadIdx.x;  // B*Z threads
  const int b = t / ZZ;
  const int j = t % ZZ;
  const int e = idx[b];
  const size_t src = ((size_t)e * BB + b) * ZZ + j;
  out_mu[t] = mu[src];
  out_lv[t] = lv[src];
}

__global__ void compact_k(const int* __restrict__ idx, int* __restrict__ counts,
                          int* __restrict__ lists) {
  __shared__ int cnt[EE];
  if (threadIdx.x < EE) cnt[threadIdx.x] = 0;
  __syncthreads();
  const int b = threadIdx.x;  // blockDim = 1024
  const int e = idx[b];
  const int pos = atomicAdd(&cnt[e], 1);
  lists[e * BB + pos] = b;
  __syncthreads();
  if (threadIdx.x < EE) counts[threadIdx.x] = cnt[threadIdx.x];
}

// ---------------------------------------------------------------------------
extern "C" void kernel_launch(void* const* d_in, const int* in_sizes, int n_in,
                              void* d_out, int out_size, void* d_ws, size_t ws_size,
                              hipStream_t stream) {
  const float* x      = (const float*)d_in[0];
  const float* eps    = (const float*)d_in[1];
  const float* enc_w1 = (const float*)d_in[2];
  const float* enc_b1 = (const float*)d_in[3];
  const float* enc_w2 = (const float*)d_in[4];
  const float* enc_b2 = (const float*)d_in[5];
  const float* mu_w   = (const float*)d_in[6];
  const float* mu_b   = (const float*)d_in[7];
  const float* lv_w   = (const float*)d_in[8];
  const float* lv_b   = (const float*)d_in[9];
  const float* dec_w1 = (const float*)d_in[10];
  const float* dec_b1 = (const float*)d_in[11];
  const float* dec_w2 = (const float*)d_in[12];
  const float* dec_b2 = (const float*)d_in[13];
  const float* dec_w3 = (const float*)d_in[14];
  const float* dec_b3 = (const float*)d_in[15];

  // Workspace layout (floats)
  float* ws   = (float*)d_ws;
  float* bufA = ws;                                   // E*B*H (H1, then HD1)
  float* bufB = bufA + (size_t)EE * BB * HH;          // E*B*H (H2, then HD2)
  float* muv  = bufB + (size_t)EE * BB * HH;          // E*B*Z
  float* lvv  = muv + (size_t)EE * BB * ZZ;           // E*B*Z
  float* zv   = lvv + (size_t)EE * BB * ZZ;           // E*B*Z
  const int NBLK = DD / BN;                           // 128
  float* part = zv + (size_t)EE * BB * ZZ;            // E*B*NBLK
  float* loss = part + (size_t)EE * BB * NBLK;        // E*B
  int* idx    = (int*)(loss + EE * BB);               // B
  int* counts = idx + BB;                             // E
  int* lists  = counts + EE;                          // E*B

  // Output layout: mu_sel | logvar_sel | xhat_sel | expert_idx(float)
  float* out_mu = (float*)d_out;
  float* out_lv = out_mu + (size_t)BB * ZZ;
  float* out_xh = out_lv + (size_t)BB * ZZ;
  float* out_ix = out_xh + (size_t)BB * DD;

  const dim3 blk(256);

  // Encoder
  gemm_k<false, true><<<dim3(HH / BN, BB / BM, EE), blk, 0, stream>>>(
      x, enc_w1, enc_b1, bufA, BB, HH, DD);
  gemm_k<true, true><<<dim3(HH / BN, BB / BM, EE), blk, 0, stream>>>(
      bufA, enc_w2, enc_b2, bufB, BB, HH, HH);
  gemm_k<true, false><<<dim3(ZZ / BN, BB / BM, EE), blk, 0, stream>>>(
      bufB, mu_w, mu_b, muv, BB, ZZ, HH);
  gemm_k<true, false><<<dim3(ZZ / BN, BB / BM, EE), blk, 0, stream>>>(
      bufB, lv_w, lv_b, lvv, BB, ZZ, HH);

  // Reparameterize
  z_k<<<dim3(EE * BB * ZZ / 256), blk, 0, stream>>>(muv, lvv, eps, zv);

  // Decoder (HD1 -> bufA, HD2 -> bufB)
  gemm_k<true, true><<<dim3(HH / BN, BB / BM, EE), blk, 0, stream>>>(
      zv, dec_w1, dec_b1, bufA, BB, HH, ZZ);
  gemm_k<true, true><<<dim3(HH / BN, BB / BM, EE), blk, 0, stream>>>(
      bufA, dec_w2, dec_b2, bufB, BB, HH, HH);

  // dec3 fused with loss partials (xhat not materialized)
  gemm_loss_k<<<dim3(DD / BN, BB / BM, EE), blk, 0, stream>>>(
      bufB, dec_w3, dec_b3, x, part, BB, DD, HH, NBLK);

  // Loss reduce, argmin, selections
  loss_reduce_k<<<dim3(EE * BB / 256), blk, 0, stream>>>(part, loss, NBLK);
  argmin_k<<<dim3(BB / 256), blk, 0, stream>>>(loss, idx, out_ix);
  select_k<<<dim3(BB * ZZ / 256), blk, 0, stream>>>(muv, lvv, idx, out_mu, out_lv);
  compact_k<<<dim3(1), dim3(1024), 0, stream>>>(idx, counts, lists);

  // Recompute xhat only for each sample's selected expert
  gemm_gather_k<<<dim3(DD / BN, BB / BM, EE), blk, 0, stream>>>(
      bufB, dec_w3, dec_b3, counts, lists, out_xh, DD, HH);
}

// Round 2
// 975.409 us; speedup vs baseline: 2.2583x; 2.2583x over previous
//
#include <hip/hip_runtime.h>

// Problem constants
#define EE 8
#define BB 1024
#define DD 8192
#define HH 512
#define ZZ 128

typedef __attribute__((ext_vector_type(8))) short bf16x8;
typedef __attribute__((ext_vector_type(4))) float f32x4;

// LDS tile row stride: 64 + 8 pad shorts -> 144 B. Verified conflict-free for
// all four access patterns (A/B stage writes, A/B fragment b128 reads).
#define LDK 72

__device__ __forceinline__ float4 ld4(const float* p) { return *(const float4*)p; }

// RNE float -> bf16 bits
__device__ __forceinline__ unsigned f2bf_u(float x) {
  unsigned u = __builtin_bit_cast(unsigned, x);
  return (u + 0x7FFFu + ((u >> 16) & 1u)) >> 16;
}
__device__ __forceinline__ float bfu2f(unsigned h) {
  return __builtin_bit_cast(float, h << 16);
}
// Split x into hi + lo bf16 (residual ~2^-18 relative)
__device__ __forceinline__ void split2(float x, short& hi, short& lo) {
  unsigned h = f2bf_u(x);
  hi = (short)h;
  float r = x - bfu2f(h);
  lo = (short)f2bf_u(r);
}

// ---------------------------------------------------------------------------
// Stage one 128x64 A-tile and 64x128 B-tile (transposed to [n][k]) as
// split hi/lo bf16 into LDS. 256 threads.
// ---------------------------------------------------------------------------
template <bool GATHER>
__device__ __forceinline__ void stage_tiles(
    const float* __restrict__ Ae, const float* __restrict__ We,
    int K, int N, int k0, int n0, int m0, const int* rows_s,
    short (*__restrict__ Ah)[LDK], short (*__restrict__ Al)[LDK],
    short (*__restrict__ Bh)[LDK], short (*__restrict__ Bl)[LDK]) {
  const int t = threadIdx.x;
  // ---- A tile: row = t>>1 (0..127), k-quarter = (t&1)*32
  {
    const int row = t >> 1;
    const int kq = (t & 1) * 32;
    bool valid = true;
    size_t arow;
    if (GATHER) {
      const int rsrc = rows_s[row];
      valid = rsrc >= 0;
      arow = (size_t)(valid ? rsrc : 0);
    } else {
      arow = (size_t)(m0 + row);
    }
    const float* ap = Ae + arow * K + k0 + kq;
#pragma unroll
    for (int c = 0; c < 4; ++c) {
      float v[8];
      if (!GATHER || valid) {
        *(float4*)&v[0] = ld4(ap + c * 8);
        *(float4*)&v[4] = ld4(ap + c * 8 + 4);
      } else {
#pragma unroll
        for (int j = 0; j < 8; ++j) v[j] = 0.0f;
      }
      short h8[8], l8[8];
#pragma unroll
      for (int j = 0; j < 8; ++j) split2(v[j], h8[j], l8[j]);
      *(bf16x8*)&Ah[row][kq + c * 8] = *(bf16x8*)h8;
      *(bf16x8*)&Al[row][kq + c * 8] = *(bf16x8*)l8;
    }
  }
  // ---- B tile: thread covers n in {nb, nb+1, nb+64, nb+65}, k in [kq, kq+8)
  {
    const int nb = (t & 31) * 2;
    const int kq = (t >> 5) * 8;
    short h[4][8], l[4][8];
#pragma unroll
    for (int dk = 0; dk < 8; ++dk) {
      const float* wp = We + (size_t)(k0 + kq + dk) * N + n0 + nb;
      const float2 v0 = *(const float2*)wp;
      const float2 v1 = *(const float2*)(wp + 64);
      split2(v0.x, h[0][dk], l[0][dk]);
      split2(v0.y, h[1][dk], l[1][dk]);
      split2(v1.x, h[2][dk], l[2][dk]);
      split2(v1.y, h[3][dk], l[3][dk]);
    }
    const int nn0 = nb, nn1 = nb + 1, nn2 = nb + 64, nn3 = nb + 65;
    *(bf16x8*)&Bh[nn0][kq] = *(bf16x8*)h[0];
    *(bf16x8*)&Bl[nn0][kq] = *(bf16x8*)l[0];
    *(bf16x8*)&Bh[nn1][kq] = *(bf16x8*)h[1];
    *(bf16x8*)&Bl[nn1][kq] = *(bf16x8*)l[1];
    *(bf16x8*)&Bh[nn2][kq] = *(bf16x8*)h[2];
    *(bf16x8*)&Bl[nn2][kq] = *(bf16x8*)l[2];
    *(bf16x8*)&Bh[nn3][kq] = *(bf16x8*)h[3];
    *(bf16x8*)&Bl[nn3][kq] = *(bf16x8*)l[3];
  }
}

// ---------------------------------------------------------------------------
// One K=64 chunk of split-bf16 MFMA: acc += Ahi*Bhi + Ahi*Blo + Alo*Bhi.
// Wave computes a 64x64 sub-tile as 4x4 fragments of 16x16x32.
// ---------------------------------------------------------------------------
__device__ __forceinline__ void mma_chunk(
    int wm, int wn, int lane,
    const short (*__restrict__ Ah)[LDK], const short (*__restrict__ Al)[LDK],
    const short (*__restrict__ Bh)[LDK], const short (*__restrict__ Bl)[LDK],
    f32x4 acc[4][4]) {
  const int g = lane >> 4, r16 = lane & 15;
#pragma unroll
  for (int kk = 0; kk < 2; ++kk) {
    const int ko = kk * 32 + g * 8;
    bf16x8 ah[4], al[4], bh[4], bl[4];
#pragma unroll
    for (int m = 0; m < 4; ++m) {
      ah[m] = *(const bf16x8*)&Ah[wm * 64 + m * 16 + r16][ko];
      al[m] = *(const bf16x8*)&Al[wm * 64 + m * 16 + r16][ko];
    }
#pragma unroll
    for (int n = 0; n < 4; ++n) {
      bh[n] = *(const bf16x8*)&Bh[wn * 64 + n * 16 + r16][ko];
      bl[n] = *(const bf16x8*)&Bl[wn * 64 + n * 16 + r16][ko];
    }
#pragma unroll
    for (int m = 0; m < 4; ++m)
#pragma unroll
      for (int n = 0; n < 4; ++n) {
        acc[m][n] = __builtin_amdgcn_mfma_f32_16x16x32_bf16(ah[m], bh[n], acc[m][n], 0, 0, 0);
        acc[m][n] = __builtin_amdgcn_mfma_f32_16x16x32_bf16(ah[m], bl[n], acc[m][n], 0, 0, 0);
        acc[m][n] = __builtin_amdgcn_mfma_f32_16x16x32_bf16(al[m], bh[n], acc[m][n], 0, 0, 0);
      }
  }
}

// ---------------------------------------------------------------------------
// Generic split-bf16 MFMA GEMM: Y = act(A @ W + bias)
// ---------------------------------------------------------------------------
template <bool APE, bool RELU>
__global__ __launch_bounds__(256, 2) void gemm_mfma_k(
    const float* __restrict__ A, const float* __restrict__ W,
    const float* __restrict__ bias, float* __restrict__ Y,
    int M, int N, int K) {
  __shared__ short Ah[128][LDK], Al[128][LDK], Bh[128][LDK], Bl[128][LDK];
  const int e = blockIdx.z;
  const int m0 = blockIdx.y * 128, n0 = blockIdx.x * 128;
  const float* Ae = APE ? A + (size_t)e * M * K : A;
  const float* We = W + (size_t)e * K * N;
  const float* be = bias + (size_t)e * N;
  float* Ye = Y + (size_t)e * M * N;

  const int t = threadIdx.x;
  const int wid = t >> 6, lane = t & 63;
  const int wm = wid >> 1, wn = wid & 1;

  f32x4 acc[4][4];
#pragma unroll
  for (int m = 0; m < 4; ++m)
#pragma unroll
    for (int n = 0; n < 4; ++n) acc[m][n] = (f32x4){0.f, 0.f, 0.f, 0.f};

  for (int k0 = 0; k0 < K; k0 += 64) {
    stage_tiles<false>(Ae, We, K, N, k0, n0, m0, nullptr, Ah, Al, Bh, Bl);
    __syncthreads();
    mma_chunk(wm, wn, lane, Ah, Al, Bh, Bl, acc);
    __syncthreads();
  }

  const int g = lane >> 4, r16 = lane & 15;
#pragma unroll
  for (int n = 0; n < 4; ++n) {
    const int cn = n0 + wn * 64 + n * 16 + r16;
    const float bv = be[cn];
#pragma unroll
    for (int m = 0; m < 4; ++m)
#pragma unroll
      for (int r = 0; r < 4; ++r) {
        const int row = m0 + wm * 64 + m * 16 + g * 4 + r;
        float v = acc[m][n][r] + bv;
        if (RELU) v = fmaxf(v, 0.0f);
        Ye[(size_t)row * N + cn] = v;
      }
  }
}

// ---------------------------------------------------------------------------
// dec3 + fused loss partials (xhat not materialized)
// ---------------------------------------------------------------------------
__global__ __launch_bounds__(256, 2) void gemm_loss_mfma_k(
    const float* __restrict__ A, const float* __restrict__ W,
    const float* __restrict__ bias, const float* __restrict__ xf,
    float* __restrict__ partials, int N, int K, int NBLK) {
  __shared__ short Ah[128][LDK], Al[128][LDK], Bh[128][LDK], Bl[128][LDK];
  __shared__ float red[128][2];
  const int e = blockIdx.z;
  const int m0 = blockIdx.y * 128, n0 = blockIdx.x * 128;
  const float* Ae = A + (size_t)e * BB * K;
  const float* We = W + (size_t)e * K * N;
  const float* be = bias + (size_t)e * N;

  const int t = threadIdx.x;
  const int wid = t >> 6, lane = t & 63;
  const int wm = wid >> 1, wn = wid & 1;

  f32x4 acc[4][4];
#pragma unroll
  for (int m = 0; m < 4; ++m)
#pragma unroll
    for (int n = 0; n < 4; ++n) acc[m][n] = (f32x4){0.f, 0.f, 0.f, 0.f};

  for (int k0 = 0; k0 < K; k0 += 64) {
    stage_tiles<false>(Ae, We, K, N, k0, n0, m0, nullptr, Ah, Al, Bh, Bl);
    __syncthreads();
    mma_chunk(wm, wn, lane, Ah, Al, Bh, Bl, acc);
    __syncthreads();
  }

  const int g = lane >> 4, r16 = lane & 15;
  float rs[4][4];
#pragma unroll
  for (int m = 0; m < 4; ++m)
#pragma unroll
    for (int r = 0; r < 4; ++r) rs[m][r] = 0.0f;

#pragma unroll
  for (int n = 0; n < 4; ++n) {
    const int cn = n0 + wn * 64 + n * 16 + r16;
    const float bv = be[cn];
#pragma unroll
    for (int m = 0; m < 4; ++m)
#pragma unroll
      for (int r = 0; r < 4; ++r) {
        const int row = m0 + wm * 64 + m * 16 + g * 4 + r;
        const float d = acc[m][n][r] + bv - xf[(size_t)row * N + cn];
        rs[m][r] = fmaf(d, d, rs[m][r]);
      }
  }
  // reduce across the 16 cols held by the 16 lanes of each group
#pragma unroll
  for (int off = 1; off < 16; off <<= 1)
#pragma unroll
    for (int m = 0; m < 4; ++m)
#pragma unroll
      for (int r = 0; r < 4; ++r) rs[m][r] += __shfl_xor(rs[m][r], off);
  if (r16 == 0) {
#pragma unroll
    for (int m = 0; m < 4; ++m)
#pragma unroll
      for (int r = 0; r < 4; ++r)
        red[wm * 64 + m * 16 + g * 4 + r][wn] = rs[m][r];
  }
  __syncthreads();
  if (t < 128) {
    partials[((size_t)e * BB + m0 + t) * NBLK + blockIdx.x] = red[t][0] + red[t][1];
  }
}

// ---------------------------------------------------------------------------
// Gathered recompute of xhat for the selected expert only
// ---------------------------------------------------------------------------
__global__ __launch_bounds__(256, 2) void gemm_gather_mfma_k(
    const float* __restrict__ A, const float* __restrict__ W,
    const float* __restrict__ bias, const int* __restrict__ counts,
    const int* __restrict__ lists, float* __restrict__ out, int N, int K) {
  __shared__ short Ah[128][LDK], Al[128][LDK], Bh[128][LDK], Bl[128][LDK];
  __shared__ int rows_s[128];
  const int e = blockIdx.z;
  const int cnt = counts[e];
  const int m0 = blockIdx.y * 128;
  if (m0 >= cnt) return;
  const int n0 = blockIdx.x * 128;
  const float* Ae = A + (size_t)e * BB * K;
  const float* We = W + (size_t)e * K * N;
  const float* be = bias + (size_t)e * N;

  const int t = threadIdx.x;
  const int wid = t >> 6, lane = t & 63;
  const int wm = wid >> 1, wn = wid & 1;

  if (t < 128) rows_s[t] = (m0 + t < cnt) ? lists[e * BB + m0 + t] : -1;
  __syncthreads();

  f32x4 acc[4][4];
#pragma unroll
  for (int m = 0; m < 4; ++m)
#pragma unroll
    for (int n = 0; n < 4; ++n) acc[m][n] = (f32x4){0.f, 0.f, 0.f, 0.f};

  for (int k0 = 0; k0 < K; k0 += 64) {
    stage_tiles<true>(Ae, We, K, N, k0, n0, m0, rows_s, Ah, Al, Bh, Bl);
    __syncthreads();
    mma_chunk(wm, wn, lane, Ah, Al, Bh, Bl, acc);
    __syncthreads();
  }

  const int g = lane >> 4, r16 = lane & 15;
#pragma unroll
  for (int n = 0; n < 4; ++n) {
    const int cn = n0 + wn * 64 + n * 16 + r16;
    const float bv = be[cn];
#pragma unroll
    for (int m = 0; m < 4; ++m)
#pragma unroll
      for (int r = 0; r < 4; ++r) {
        const int rout = rows_s[wm * 64 + m * 16 + g * 4 + r];
        if (rout >= 0) out[(size_t)rout * N + cn] = acc[m][n][r] + bv;
      }
  }
}

// ---------------------------------------------------------------------------
// Small kernels
// ---------------------------------------------------------------------------
__global__ void z_k(const float* __restrict__ mu, const float* __restrict__ lv,
                    const float* __restrict__ eps, float* __restrict__ z) {
  const int t = blockIdx.x * blockDim.x + threadIdx.x;
  z[t] = fmaf(expf(0.5f * lv[t]), eps[t], mu[t]);
}

__global__ void loss_reduce_k(const float* __restrict__ partials,
                              float* __restrict__ losses, int NBLK) {
  const int id = blockIdx.x * blockDim.x + threadIdx.x;  // E*B threads
  const float* p = partials + (size_t)id * NBLK;
  float s = 0.0f;
  for (int j = 0; j < NBLK; ++j) s += p[j];
  losses[id] = s;
}

__global__ void argmin_k(const float* __restrict__ losses, int* __restrict__ idx,
                         float* __restrict__ out_ix) {
  const int b = blockIdx.x * blockDim.x + threadIdx.x;  // B threads
  float best = losses[b];
  int bi = 0;
#pragma unroll
  for (int e = 1; e < EE; ++e) {
    const float v = losses[e * BB + b];
    if (v < best) { best = v; bi = e; }
  }
  idx[b] = bi;
  out_ix[b] = (float)bi;
}

__global__ void select_k(const float* __restrict__ mu, const float* __restrict__ lv,
                         const int* __restrict__ idx, float* __restrict__ out_mu,
                         float* __restrict__ out_lv) {
  const int t = blockIdx.x * blockDim.x + threadIdx.x;  // B*Z threads
  const int b = t / ZZ;
  const int j = t % ZZ;
  const int e = idx[b];
  const size_t src = ((size_t)e * BB + b) * ZZ + j;
  out_mu[t] = mu[src];
  out_lv[t] = lv[src];
}

__global__ void compact_k(const int* __restrict__ idx, int* __restrict__ counts,
                          int* __restrict__ lists) {
  __shared__ int cnt[EE];
  if (threadIdx.x < EE) cnt[threadIdx.x] = 0;
  __syncthreads();
  const int b = threadIdx.x;  // blockDim = 1024
  const int e = idx[b];
  const int pos = atomicAdd(&cnt[e], 1);
  lists[e * BB + pos] = b;
  __syncthreads();
  if (threadIdx.x < EE) counts[threadIdx.x] = cnt[threadIdx.x];
}

// ---------------------------------------------------------------------------
extern "C" void kernel_launch(void* const* d_in, const int* in_sizes, int n_in,
                              void* d_out, int out_size, void* d_ws, size_t ws_size,
                              hipStream_t stream) {
  const float* x      = (const float*)d_in[0];
  const float* eps    = (const float*)d_in[1];
  const float* enc_w1 = (const float*)d_in[2];
  const float* enc_b1 = (const float*)d_in[3];
  const float* enc_w2 = (const float*)d_in[4];
  const float* enc_b2 = (const float*)d_in[5];
  const float* mu_w   = (const float*)d_in[6];
  const float* mu_b   = (const float*)d_in[7];
  const float* lv_w   = (const float*)d_in[8];
  const float* lv_b   = (const float*)d_in[9];
  const float* dec_w1 = (const float*)d_in[10];
  const float* dec_b1 = (const float*)d_in[11];
  const float* dec_w2 = (const float*)d_in[12];
  const float* dec_b2 = (const float*)d_in[13];
  const float* dec_w3 = (const float*)d_in[14];
  const float* dec_b3 = (const float*)d_in[15];

  // Workspace layout (floats)
  const int NBLK = DD / 128;                          // 64
  float* ws   = (float*)d_ws;
  float* bufA = ws;                                   // E*B*H (H1, then HD1)
  float* bufB = bufA + (size_t)EE * BB * HH;          // E*B*H (H2, then HD2)
  float* muv  = bufB + (size_t)EE * BB * HH;          // E*B*Z
  float* lvv  = muv + (size_t)EE * BB * ZZ;           // E*B*Z
  float* zv   = lvv + (size_t)EE * BB * ZZ;           // E*B*Z
  float* part = zv + (size_t)EE * BB * ZZ;            // E*B*NBLK
  float* loss = part + (size_t)EE * BB * NBLK;        // E*B
  int* idx    = (int*)(loss + EE * BB);               // B
  int* counts = idx + BB;                             // E
  int* lists  = counts + EE;                          // E*B

  // Output layout: mu_sel | logvar_sel | xhat_sel | expert_idx(float)
  float* out_mu = (float*)d_out;
  float* out_lv = out_mu + (size_t)BB * ZZ;
  float* out_xh = out_lv + (size_t)BB * ZZ;
  float* out_ix = out_xh + (size_t)BB * DD;

  const dim3 blk(256);

  // Encoder
  gemm_mfma_k<false, true><<<dim3(HH / 128, BB / 128, EE), blk, 0, stream>>>(
      x, enc_w1, enc_b1, bufA, BB, HH, DD);
  gemm_mfma_k<true, true><<<dim3(HH / 128, BB / 128, EE), blk, 0, stream>>>(
      bufA, enc_w2, enc_b2, bufB, BB, HH, HH);
  gemm_mfma_k<true, false><<<dim3(ZZ / 128, BB / 128, EE), blk, 0, stream>>>(
      bufB, mu_w, mu_b, muv, BB, ZZ, HH);
  gemm_mfma_k<true, false><<<dim3(ZZ / 128, BB / 128, EE), blk, 0, stream>>>(
      bufB, lv_w, lv_b, lvv, BB, ZZ, HH);

  // Reparameterize
  z_k<<<dim3(EE * BB * ZZ / 256), blk, 0, stream>>>(muv, lvv, eps, zv);

  // Decoder (HD1 -> bufA, HD2 -> bufB)
  gemm_mfma_k<true, true><<<dim3(HH / 128, BB / 128, EE), blk, 0, stream>>>(
      zv, dec_w1, dec_b1, bufA, BB, HH, ZZ);
  gemm_mfma_k<true, true><<<dim3(HH / 128, BB / 128, EE), blk, 0, stream>>>(
      bufA, dec_w2, dec_b2, bufB, BB, HH, HH);

  // dec3 fused with loss partials
  gemm_loss_mfma_k<<<dim3(DD / 128, BB / 128, EE), blk, 0, stream>>>(
      bufB, dec_w3, dec_b3, x, part, DD, HH, NBLK);

  // Loss reduce, argmin, selections
  loss_reduce_k<<<dim3(EE * BB / 256), blk, 0, stream>>>(part, loss, NBLK);
  argmin_k<<<dim3(BB / 256), blk, 0, stream>>>(loss, idx, out_ix);
  select_k<<<dim3(BB * ZZ / 256), blk, 0, stream>>>(muv, lvv, idx, out_mu, out_lv);
  compact_k<<<dim3(1), dim3(1024), 0, stream>>>(idx, counts, lists);

  // Recompute xhat only for each sample's selected expert
  gemm_gather_mfma_k<<<dim3(DD / 128, BB / 128, EE), blk, 0, stream>>>(
      bufB, dec_w3, dec_b3, counts, lists, out_xh, DD, HH);
}

// Round 3
// 878.909 us; speedup vs baseline: 2.5062x; 1.1098x over previous
//
#include <hip/hip_runtime.h>

// Problem constants
#define EE 8
#define BB 1024
#define DD 8192
#define HH 512
#define ZZ 128

typedef __attribute__((ext_vector_type(8))) short bf16x8;
typedef __attribute__((ext_vector_type(4))) float f32x4;
typedef __attribute__((address_space(1))) unsigned int u32g;
typedef __attribute__((address_space(3))) unsigned int u32l;

#define DEVI __device__ __forceinline__

DEVI float4 ld4(const float* p) { return *(const float4*)p; }

// RNE float -> bf16 bits
DEVI unsigned f2bf_u(float x) {
  unsigned u = __builtin_bit_cast(unsigned, x);
  return (u + 0x7FFFu + ((u >> 16) & 1u)) >> 16;
}
DEVI float bfu2f(unsigned h) { return __builtin_bit_cast(float, h << 16); }
DEVI void split2(float x, short& hi, short& lo) {
  unsigned h = f2bf_u(x);
  hi = (short)h;
  lo = (short)f2bf_u(x - bfu2f(h));
}

// Direct global->LDS async copy, 16B per lane. LDS dest is wave-uniform
// base + lane*16 (linear); swizzle is applied on the global SOURCE address.
DEVI void gload16(const void* g, void* l) {
  __builtin_amdgcn_global_load_lds((const u32g*)g, (u32l*)l, 16, 0, 0);
}

// Stage a ROWS x 64 bf16 tile. src points at (tile row0, k0). Kb = row stride
// in bytes. laneoff = (w*8 + (lane>>3))*Kb + (((lane&7) ^ ((lane>>3)&7))<<4)
// (the XOR pre-swizzles the source so swizzled reads are conflict-free).
template <int ROWS>
DEVI void stage1(const short* src, int Kb, short* lds, int w, int lane, int laneoff) {
  const char* p = (const char*)src + laneoff;
  char* l = (char*)lds + w * 1024;
#pragma unroll
  for (int r = 0; r < ROWS / 32; ++r)
    gload16(p + (size_t)r * 32 * Kb, l + r * 4096);
}

// One K=64 chunk. NPASS=1: acc += Ah*Bh. NPASS=3: + Ah*Bl + Al*Bh.
// Read addr: row*128 + ((kk*64 + g*16) ^ ((row&7)<<4)); abase/bbase carry the
// row*128 + swizzled g*16 part, kk toggles bit 6 via XOR.
template <int NPASS, int NF>
DEVI void mma_chunk(const char* Ah, const char* Al, const char* Bh, const char* Bl,
                    int abase, int bbase, f32x4 acc[4][NF]) {
#pragma unroll
  for (int kk = 0; kk < 2; ++kk) {
    const int kx = kk * 64;
    bf16x8 ah[4], al[4], bh[NF], bl[NF];
#pragma unroll
    for (int m = 0; m < 4; ++m) {
      ah[m] = *(const bf16x8*)(Ah + ((abase + m * 2048) ^ kx));
      if (NPASS == 3) al[m] = *(const bf16x8*)(Al + ((abase + m * 2048) ^ kx));
    }
#pragma unroll
    for (int n = 0; n < NF; ++n) {
      bh[n] = *(const bf16x8*)(Bh + ((bbase + n * 2048) ^ kx));
      if (NPASS == 3) bl[n] = *(const bf16x8*)(Bl + ((bbase + n * 2048) ^ kx));
    }
#pragma unroll
    for (int m = 0; m < 4; ++m)
#pragma unroll
      for (int n = 0; n < NF; ++n) {
        acc[m][n] = __builtin_amdgcn_mfma_f32_16x16x32_bf16(ah[m], bh[n], acc[m][n], 0, 0, 0);
        if (NPASS == 3) {
          acc[m][n] = __builtin_amdgcn_mfma_f32_16x16x32_bf16(ah[m], bl[n], acc[m][n], 0, 0, 0);
          acc[m][n] = __builtin_amdgcn_mfma_f32_16x16x32_bf16(al[m], bh[n], acc[m][n], 0, 0, 0);
        }
      }
  }
}

// ---------------------------------------------------------------------------
// GEMM: Y = act(A @ B^T + bias). A: [M,K] or [E,M,K] bf16(h/l); B: [E,N,K]
// bf16(h/l) (pre-transposed weights); OUT=0: f32 Y; OUT=1: bf16 Yh (+Yl if
// NPASS==3). 256 thr, 4 waves, tile 128 x (NF*32), BK=64.
// cntPtr: optional row limit (padded to 128) for re-resolve passes.
// ---------------------------------------------------------------------------
template <int NPASS, int NF, bool RELU, int OUT>
__global__ __launch_bounds__(256, (NPASS == 3 ? 2 : 3)) void gemm_k(
    const short* __restrict__ Ahg, const short* __restrict__ Alg,
    const short* __restrict__ Bhg, const short* __restrict__ Blg,
    const float* __restrict__ bias,
    float* __restrict__ Yf, short* __restrict__ Yh, short* __restrict__ Yl,
    int M, int N, int K, int APE, const int* __restrict__ cntPtr) {
  constexpr int BN = NF * 32;
  __shared__ short sA[(NPASS == 3 ? 2 : 1) * 128 * 64];
  __shared__ short sB[(NPASS == 3 ? 2 : 1) * BN * 64];
  const int e = blockIdx.z;
  const int m0 = blockIdx.y * 128, n0 = blockIdx.x * BN;
  if (cntPtr) {
    if (m0 >= ((cntPtr[0] + 127) & ~127)) return;
  }
  const size_t eA = APE ? (size_t)e * M * K : 0;
  const short* Ae = Ahg + eA + (size_t)m0 * K;
  const short* Ale = (NPASS == 3) ? (Alg + eA + (size_t)m0 * K) : nullptr;
  const short* Be = Bhg + ((size_t)e * N + n0) * K;
  const short* Ble = (NPASS == 3) ? (Blg + ((size_t)e * N + n0) * K) : nullptr;

  const int t = threadIdx.x, w = t >> 6, lane = t & 63;
  const int wm = w >> 1, wn = w & 1;
  const int Kb = K * 2;
  const int laneoff = (w * 8 + (lane >> 3)) * Kb + (((lane & 7) ^ ((lane >> 3) & 7)) << 4);
  const int r16 = lane & 15, g = lane >> 4;
  const int c0 = ((g ^ (r16 & 7)) << 4);
  const int abase = (wm * 64 + r16) * 128 + c0;
  const int bbase = (wn * (NF * 16) + r16) * 128 + c0;

  f32x4 acc[4][NF];
#pragma unroll
  for (int m = 0; m < 4; ++m)
#pragma unroll
    for (int n = 0; n < NF; ++n) acc[m][n] = (f32x4){0.f, 0.f, 0.f, 0.f};

  for (int k0 = 0; k0 < K; k0 += 64) {
    stage1<128>(Ae + k0, Kb, sA, w, lane, laneoff);
    if (NPASS == 3) stage1<128>(Ale + k0, Kb, sA + 128 * 64, w, lane, laneoff);
    stage1<BN>(Be + k0, Kb, sB, w, lane, laneoff);
    if (NPASS == 3) stage1<BN>(Ble + k0, Kb, sB + BN * 64, w, lane, laneoff);
    __syncthreads();
    mma_chunk<NPASS, NF>((const char*)sA, (const char*)(sA + 128 * 64),
                         (const char*)sB, (const char*)(sB + BN * 64), abase, bbase, acc);
    __syncthreads();
  }

  const int col0 = n0 + wn * (NF * 16);
#pragma unroll
  for (int n = 0; n < NF; ++n) {
    const int cn = col0 + n * 16 + r16;
    const float bv = bias[(size_t)e * N + cn];
#pragma unroll
    for (int m = 0; m < 4; ++m)
#pragma unroll
      for (int r = 0; r < 4; ++r) {
        const int row = m0 + wm * 64 + m * 16 + g * 4 + r;
        float v = acc[m][n][r] + bv;
        if (RELU) v = fmaxf(v, 0.f);
        const size_t o = ((size_t)e * M + row) * N + cn;
        if (OUT == 0) {
          Yf[o] = v;
        } else {
          unsigned hb = f2bf_u(v);
          Yh[o] = (short)hb;
          if (NPASS == 3) Yl[o] = (short)f2bf_u(v - bfu2f(hb));
        }
      }
  }
}

// ---------------------------------------------------------------------------
// dec3 + fused loss partials (NF=4). rows/cntPtr non-null for re-resolve.
// ---------------------------------------------------------------------------
template <int NPASS>
__global__ __launch_bounds__(256, 2) void gemm_loss_k(
    const short* __restrict__ Ahg, const short* __restrict__ Alg,
    const short* __restrict__ Bhg, const short* __restrict__ Blg,
    const float* __restrict__ bias, const float* __restrict__ xf,
    const int* __restrict__ rows, const int* __restrict__ cntPtr,
    float* __restrict__ partials, int K) {
  constexpr int NF = 4;
  __shared__ short sA[(NPASS == 3 ? 2 : 1) * 128 * 64];
  __shared__ short sB[(NPASS == 3 ? 2 : 1) * 128 * 64];
  __shared__ float red[128][2];
  const int e = blockIdx.z;
  const int m0 = blockIdx.y * 128, n0 = blockIdx.x * 128;
  int cntA = BB;
  if (cntPtr) {
    cntA = cntPtr[0];
    if (m0 >= ((cntA + 127) & ~127)) return;
  }
  const short* Ae = Ahg + ((size_t)e * BB + m0) * K;
  const short* Ale = (NPASS == 3) ? (Alg + ((size_t)e * BB + m0) * K) : nullptr;
  const short* Be = Bhg + ((size_t)e * DD + n0) * K;
  const short* Ble = (NPASS == 3) ? (Blg + ((size_t)e * DD + n0) * K) : nullptr;

  const int t = threadIdx.x, w = t >> 6, lane = t & 63;
  const int wm = w >> 1, wn = w & 1;
  const int Kb = K * 2;
  const int laneoff = (w * 8 + (lane >> 3)) * Kb + (((lane & 7) ^ ((lane >> 3) & 7)) << 4);
  const int r16 = lane & 15, g = lane >> 4;
  const int c0 = ((g ^ (r16 & 7)) << 4);
  const int abase = (wm * 64 + r16) * 128 + c0;
  const int bbase = (wn * 64 + r16) * 128 + c0;

  f32x4 acc[4][NF];
#pragma unroll
  for (int m = 0; m < 4; ++m)
#pragma unroll
    for (int n = 0; n < NF; ++n) acc[m][n] = (f32x4){0.f, 0.f, 0.f, 0.f};

  for (int k0 = 0; k0 < K; k0 += 64) {
    stage1<128>(Ae + k0, Kb, sA, w, lane, laneoff);
    if (NPASS == 3) stage1<128>(Ale + k0, Kb, sA + 128 * 64, w, lane, laneoff);
    stage1<128>(Be + k0, Kb, sB, w, lane, laneoff);
    if (NPASS == 3) stage1<128>(Ble + k0, Kb, sB + 128 * 64, w, lane, laneoff);
    __syncthreads();
    mma_chunk<NPASS, NF>((const char*)sA, (const char*)(sA + 128 * 64),
                         (const char*)sB, (const char*)(sB + 128 * 64), abase, bbase, acc);
    __syncthreads();
  }

  float rs[4][4];
#pragma unroll
  for (int m = 0; m < 4; ++m)
#pragma unroll
    for (int r = 0; r < 4; ++r) rs[m][r] = 0.f;
#pragma unroll
  for (int n = 0; n < NF; ++n) {
    const int cn = n0 + wn * 64 + n * 16 + r16;
    const float bv = bias[(size_t)e * DD + cn];
#pragma unroll
    for (int m = 0; m < 4; ++m)
#pragma unroll
      for (int r = 0; r < 4; ++r) {
        const int lrow = m0 + wm * 64 + m * 16 + g * 4 + r;
        const int xr = rows ? (lrow < cntA ? rows[lrow] : 0) : lrow;
        const float d = acc[m][n][r] + bv - xf[(size_t)xr * DD + cn];
        rs[m][r] = fmaf(d, d, rs[m][r]);
      }
  }
#pragma unroll
  for (int off = 1; off < 16; off <<= 1)
#pragma unroll
    for (int m = 0; m < 4; ++m)
#pragma unroll
      for (int r = 0; r < 4; ++r) rs[m][r] += __shfl_xor(rs[m][r], off);
  if (r16 == 0) {
#pragma unroll
    for (int m = 0; m < 4; ++m)
#pragma unroll
      for (int r = 0; r < 4; ++r) red[wm * 64 + m * 16 + g * 4 + r][wn] = rs[m][r];
  }
  __syncthreads();
  if (t < 128)
    partials[((size_t)e * BB + m0 + t) * 64 + blockIdx.x] = red[t][0] + red[t][1];
}

// ---------------------------------------------------------------------------
// Final xhat recompute for selected experts only (NPASS=1, NF=4, gathered A).
// ---------------------------------------------------------------------------
__global__ __launch_bounds__(256, 3) void gather_out_k(
    const short* __restrict__ Ahg, const short* __restrict__ Bhg,
    const float* __restrict__ bias, const int* __restrict__ counts,
    const int* __restrict__ lists, float* __restrict__ out, int N, int K) {
  __shared__ short sA[128 * 64];
  __shared__ short sB[128 * 64];
  __shared__ int rows_s[128];
  const int e = blockIdx.z;
  const int cnt = counts[e];
  const int m0 = blockIdx.y * 128;
  if (m0 >= cnt) return;
  const int n0 = blockIdx.x * 128;
  const short* Ae = Ahg + (size_t)e * BB * K;
  const short* Be = Bhg + ((size_t)e * N + n0) * K;

  const int t = threadIdx.x, w = t >> 6, lane = t & 63;
  const int wm = w >> 1, wn = w & 1;
  const int Kb = K * 2;
  const int csw16 = ((lane & 7) ^ ((lane >> 3) & 7)) << 4;
  const int laneoff = (w * 8 + (lane >> 3)) * Kb + csw16;
  const int r16 = lane & 15, g = lane >> 4;
  const int c0 = ((g ^ (r16 & 7)) << 4);
  const int abase = (wm * 64 + r16) * 128 + c0;
  const int bbase = (wn * 64 + r16) * 128 + c0;

  if (t < 128) rows_s[t] = (m0 + t < cnt) ? lists[e * BB + m0 + t] : -1;
  __syncthreads();
  int grow[4];
#pragma unroll
  for (int r = 0; r < 4; ++r) {
    int rr = rows_s[w * 8 + (lane >> 3) + 32 * r];
    grow[r] = rr < 0 ? 0 : rr;
  }

  f32x4 acc[4][4];
#pragma unroll
  for (int m = 0; m < 4; ++m)
#pragma unroll
    for (int n = 0; n < 4; ++n) acc[m][n] = (f32x4){0.f, 0.f, 0.f, 0.f};

  for (int k0 = 0; k0 < K; k0 += 64) {
#pragma unroll
    for (int r = 0; r < 4; ++r)
      gload16((const char*)Ae + (size_t)grow[r] * Kb + k0 * 2 + csw16,
              (char*)sA + r * 4096 + w * 1024);
    stage1<128>(Be + k0, Kb, sB, w, lane, laneoff);
    __syncthreads();
    mma_chunk<1, 4>((const char*)sA, nullptr, (const char*)sB, nullptr, abase, bbase, acc);
    __syncthreads();
  }

#pragma unroll
  for (int n = 0; n < 4; ++n) {
    const int cn = n0 + wn * 64 + n * 16 + r16;
    const float bv = bias[(size_t)e * N + cn];
#pragma unroll
    for (int m = 0; m < 4; ++m)
#pragma unroll
      for (int r = 0; r < 4; ++r) {
        const int rout = rows_s[wm * 64 + m * 16 + g * 4 + r];
        if (rout >= 0) out[(size_t)rout * N + cn] = acc[m][n][r] + bv;
      }
  }
}

// ---------------------------------------------------------------------------
// Prep / small kernels
// ---------------------------------------------------------------------------
__global__ void init_k(int* ambc) { ambc[0] = 0; }

__global__ void split_x_k(const float* __restrict__ x, short* __restrict__ Xh) {
  const int i = (blockIdx.x * 256 + threadIdx.x) * 8;
  float v[8];
  *(float4*)&v[0] = ld4(x + i);
  *(float4*)&v[4] = ld4(x + i + 4);
  short h[8];
#pragma unroll
  for (int j = 0; j < 8; ++j) h[j] = (short)f2bf_u(v[j]);
  *(bf16x8*)&Xh[i] = *(bf16x8*)h;
}

__global__ void biascat_k(const float* __restrict__ mu_b, const float* __restrict__ lv_b,
                          float* __restrict__ mlvB) {
  const int e = blockIdx.x, t = threadIdx.x;
  mlvB[e * 256 + t] = t < 128 ? mu_b[e * 128 + t] : lv_b[e * 128 + t - 128];
}

// W [E][K][N] f32 -> Th/Tl [E][rowsPerE][K] bf16 hi/lo (transposed, K-major)
__global__ __launch_bounds__(256) void trans_split_k(
    const float* __restrict__ W, short* __restrict__ Th, short* __restrict__ Tl,
    int K, int N, int rowOff, int rowsPerE) {
  const int e = blockIdx.z;
  const int k0 = blockIdx.x * 64, n0 = blockIdx.y * 64;
  __shared__ float tile[64][65];
  const int t = threadIdx.x;
  const int tr = t >> 2, tc = (t & 3) * 16;
  const float* Wp = W + ((size_t)e * K + k0 + tr) * N + n0 + tc;
#pragma unroll
  for (int c = 0; c < 4; ++c) {
    float4 v = *(const float4*)(Wp + c * 4);
    tile[tr][tc + c * 4 + 0] = v.x;
    tile[tr][tc + c * 4 + 1] = v.y;
    tile[tr][tc + c * 4 + 2] = v.z;
    tile[tr][tc + c * 4 + 3] = v.w;
  }
  __syncthreads();
  short h8[16], l8[16];
#pragma unroll
  for (int j = 0; j < 16; ++j) split2(tile[tc + j][tr], h8[j], l8[j]);
  const size_t o = ((size_t)e * rowsPerE + rowOff + n0 + tr) * K + k0 + tc;
  *(bf16x8*)&Th[o] = *(bf16x8*)&h8[0];
  *(bf16x8*)&Th[o + 8] = *(bf16x8*)&h8[8];
  *(bf16x8*)&Tl[o] = *(bf16x8*)&l8[0];
  *(bf16x8*)&Tl[o + 8] = *(bf16x8*)&l8[8];
}

__global__ void z_k(const float* __restrict__ mlv, const float* __restrict__ eps,
                    short* __restrict__ Zh) {
  const int t = blockIdx.x * 256 + threadIdx.x;  // E*B*Z
  const int eb = t >> 7, z = t & 127;
  const float mu = mlv[(size_t)eb * 256 + z], lv = mlv[(size_t)eb * 256 + 128 + z];
  Zh[t] = (short)f2bf_u(fmaf(expf(0.5f * lv), eps[t], mu));
}

__global__ void zP_k(const float* __restrict__ mlvP, const float* __restrict__ eps,
                     const int* __restrict__ ambc, const int* __restrict__ amb,
                     short* __restrict__ ZgH, short* __restrict__ ZgL) {
  const int t = blockIdx.x * 256 + threadIdx.x;  // E*1024*Z
  const int eb = t >> 7, z = t & 127;
  const int e = eb >> 10, i = eb & 1023;
  const int cntA = ambc[0];
  if (i >= ((cntA + 127) & ~127)) return;
  const int b = (i < cntA) ? amb[i] : 0;
  const float mu = mlvP[(size_t)eb * 256 + z], lv = mlvP[(size_t)eb * 256 + 128 + z];
  const float v = fmaf(expf(0.5f * lv), eps[((size_t)e * BB + b) * ZZ + z], mu);
  short h, l;
  split2(v, h, l);
  ZgH[t] = h;
  ZgL[t] = l;
}

__global__ void gather_x_k(const float* __restrict__ x, const int* __restrict__ ambc,
                           const int* __restrict__ amb, short* __restrict__ XgH,
                           short* __restrict__ XgL) {
  const int i = blockIdx.x;
  const int cntA = ambc[0];
  if (i >= ((cntA + 127) & ~127)) return;
  const int b = (i < cntA) ? amb[i] : 0;
  const float* xr = x + (size_t)b * DD;
  short* oh = XgH + (size_t)i * DD;
  short* ol = XgL + (size_t)i * DD;
  for (int j = threadIdx.x * 8; j < DD; j += 256 * 8) {
    float v[8];
    *(float4*)&v[0] = ld4(xr + j);
    *(float4*)&v[4] = ld4(xr + j + 4);
    short h[8], l[8];
#pragma unroll
    for (int q = 0; q < 8; ++q) split2(v[q], h[q], l[q]);
    *(bf16x8*)&oh[j] = *(bf16x8*)h;
    *(bf16x8*)&ol[j] = *(bf16x8*)l;
  }
}

__global__ void loss_reduce_k(const float* __restrict__ part, float* __restrict__ loss,
                              const int* __restrict__ cntPtr) {
  const int id = blockIdx.x * 256 + threadIdx.x;  // E*1024
  if (cntPtr) {
    if ((id & 1023) >= ((cntPtr[0] + 127) & ~127)) return;
  }
  const float* p = part + (size_t)id * 64;
  float s = 0.f;
#pragma unroll
  for (int j = 0; j < 64; ++j) s += p[j];
  loss[id] = s;
}

__global__ void argmin_flag_k(const float* __restrict__ loss, int* __restrict__ idx,
                              float* __restrict__ out_ix, int* __restrict__ ambc,
                              int* __restrict__ amb) {
  const int b = blockIdx.x * 256 + threadIdx.x;
  float best = loss[b], sec = 3.0e38f;
  int bi = 0;
#pragma unroll
  for (int e = 1; e < EE; ++e) {
    const float v = loss[e * BB + b];
    if (v < best) { sec = best; best = v; bi = e; }
    else if (v < sec) sec = v;
  }
  idx[b] = bi;
  out_ix[b] = (float)bi;
  // flag samples whose bf16-chain loss gap could be ambiguous
  if (sec - best < 30.0f + 0.003f * best) {
    int p = atomicAdd(ambc, 1);
    amb[p] = b;
  }
}

__global__ void fix_idx_k(const float* __restrict__ lossP, const int* __restrict__ ambc,
                          const int* __restrict__ amb, int* __restrict__ idx,
                          float* __restrict__ out_ix) {
  const int i = blockIdx.x * 256 + threadIdx.x;
  if (i >= ambc[0]) return;
  const int b = amb[i];
  float best = lossP[i];
  int bi = 0;
#pragma unroll
  for (int e = 1; e < EE; ++e) {
    const float v = lossP[e * 1024 + i];
    if (v < best) { best = v; bi = e; }
  }
  idx[b] = bi;
  out_ix[b] = (float)bi;
}

__global__ void select_k(const float* __restrict__ mlv, const int* __restrict__ idx,
                         float* __restrict__ out_mu, float* __restrict__ out_lv) {
  const int t = blockIdx.x * 256 + threadIdx.x;  // B*Z
  const int b = t >> 7, z = t & 127;
  const int e = idx[b];
  out_mu[t] = mlv[((size_t)(e * BB + b)) * 256 + z];
  out_lv[t] = mlv[((size_t)(e * BB + b)) * 256 + 128 + z];
}

__global__ void compact_k(const int* __restrict__ idx, int* __restrict__ counts,
                          int* __restrict__ lists) {
  __shared__ int cnt[EE];
  if (threadIdx.x < EE) cnt[threadIdx.x] = 0;
  __syncthreads();
  const int b = threadIdx.x;  // blockDim = 1024
  const int e = idx[b];
  const int pos = atomicAdd(&cnt[e], 1);
  lists[e * BB + pos] = b;
  __syncthreads();
  if (threadIdx.x < EE) counts[threadIdx.x] = cnt[threadIdx.x];
}

// ---------------------------------------------------------------------------
extern "C" void kernel_launch(void* const* d_in, const int* in_sizes, int n_in,
                              void* d_out, int out_size, void* d_ws, size_t ws_size,
                              hipStream_t stream) {
  const float* x      = (const float*)d_in[0];
  const float* eps    = (const float*)d_in[1];
  const float* enc_w1 = (const float*)d_in[2];
  const float* enc_b1 = (const float*)d_in[3];
  const float* enc_w2 = (const float*)d_in[4];
  const float* enc_b2 = (const float*)d_in[5];
  const float* mu_b   = (const float*)d_in[7];
  const float* mu_w   = (const float*)d_in[6];
  const float* lv_w   = (const float*)d_in[8];
  const float* lv_b   = (const float*)d_in[9];
  const float* dec_w1 = (const float*)d_in[10];
  const float* dec_b1 = (const float*)d_in[11];
  const float* dec_w2 = (const float*)d_in[12];
  const float* dec_b2 = (const float*)d_in[13];
  const float* dec_w3 = (const float*)d_in[14];
  const float* dec_b3 = (const float*)d_in[15];

  // Workspace carve-out (~385 MB)
  char* wsb = (char*)d_ws;
  size_t off = 0;
  auto alloc = [&](size_t bytes) -> void* {
    void* p = wsb + off;
    off = (off + bytes + 511) & ~(size_t)511;
    return p;
  };
  short* Xh    = (short*)alloc(16777216);   // x bf16 (reused as XgH later)
  short* ew1Th = (short*)alloc(67108864);
  short* ew1Tl = (short*)alloc(67108864);
  short* ew2Th = (short*)alloc(4194304);
  short* ew2Tl = (short*)alloc(4194304);
  short* mlvTh = (short*)alloc(2097152);
  short* mlvTl = (short*)alloc(2097152);
  short* dw1Th = (short*)alloc(1048576);
  short* dw1Tl = (short*)alloc(1048576);
  short* dw2Th = (short*)alloc(4194304);
  short* dw2Tl = (short*)alloc(4194304);
  short* dw3Th = (short*)alloc(67108864);
  short* dw3Tl = (short*)alloc(67108864);
  short* Hh    = (short*)alloc(8388608);    // enc h1, later HD1
  short* H2h   = (short*)alloc(8388608);    // enc h2, later HD2
  float* mlv   = (float*)alloc(8388608);    // [E][B][256] mu|lv
  float* mlvB  = (float*)alloc(8192);
  short* Zh    = (short*)alloc(2097152);
  float* part  = (float*)alloc(2097152);    // also partP
  float* loss  = (float*)alloc(32768);
  int*   idx   = (int*)alloc(4096);
  int*   ambc  = (int*)alloc(512);
  int*   amb   = (int*)alloc(4096);
  int*   counts= (int*)alloc(512);
  int*   lists = (int*)alloc(4096);
  short* XgL   = (short*)alloc(16777216);
  short* PAh   = (short*)alloc(8388608);
  short* PAl   = (short*)alloc(8388608);
  short* PBh   = (short*)alloc(8388608);
  short* PBl   = (short*)alloc(8388608);
  float* mlvP  = (float*)alloc(8388608);
  short* ZgH   = (short*)alloc(2097152);
  short* ZgL   = (short*)alloc(2097152);
  float* lossP = (float*)alloc(32768);
  short* XgH   = Xh;  // alias: Xh dead after enc1-main

  float* out_mu = (float*)d_out;
  float* out_lv = out_mu + (size_t)BB * ZZ;
  float* out_xh = out_lv + (size_t)BB * ZZ;
  float* out_ix = out_xh + (size_t)BB * DD;

  const dim3 blk(256);

  // Prep: conversions / transposes (run every launch; deterministic)
  init_k<<<1, 1, 0, stream>>>(ambc);
  split_x_k<<<4096, blk, 0, stream>>>(x, Xh);
  biascat_k<<<8, blk, 0, stream>>>(mu_b, lv_b, mlvB);
  trans_split_k<<<dim3(128, 8, 8), blk, 0, stream>>>(enc_w1, ew1Th, ew1Tl, 8192, 512, 0, 512);
  trans_split_k<<<dim3(8, 8, 8), blk, 0, stream>>>(enc_w2, ew2Th, ew2Tl, 512, 512, 0, 512);
  trans_split_k<<<dim3(8, 2, 8), blk, 0, stream>>>(mu_w, mlvTh, mlvTl, 512, 128, 0, 256);
  trans_split_k<<<dim3(8, 2, 8), blk, 0, stream>>>(lv_w, mlvTh, mlvTl, 512, 128, 128, 256);
  trans_split_k<<<dim3(2, 8, 8), blk, 0, stream>>>(dec_w1, dw1Th, dw1Tl, 128, 512, 0, 512);
  trans_split_k<<<dim3(8, 8, 8), blk, 0, stream>>>(dec_w2, dw2Th, dw2Tl, 512, 512, 0, 512);
  trans_split_k<<<dim3(8, 128, 8), blk, 0, stream>>>(dec_w3, dw3Th, dw3Tl, 512, 8192, 0, 8192);

  // Main chain: 1-pass bf16
  gemm_k<1, 2, true, 1><<<dim3(8, 8, 8), blk, 0, stream>>>(
      Xh, nullptr, ew1Th, nullptr, enc_b1, nullptr, Hh, nullptr, 1024, 512, 8192, 0, nullptr);
  gemm_k<1, 2, true, 1><<<dim3(8, 8, 8), blk, 0, stream>>>(
      Hh, nullptr, ew2Th, nullptr, enc_b2, nullptr, H2h, nullptr, 1024, 512, 512, 1, nullptr);
  gemm_k<1, 2, false, 0><<<dim3(4, 8, 8), blk, 0, stream>>>(
      H2h, nullptr, mlvTh, nullptr, mlvB, mlv, nullptr, nullptr, 1024, 256, 512, 1, nullptr);
  z_k<<<4096, blk, 0, stream>>>(mlv, eps, Zh);
  gemm_k<1, 2, true, 1><<<dim3(8, 8, 8), blk, 0, stream>>>(
      Zh, nullptr, dw1Th, nullptr, dec_b1, nullptr, Hh, nullptr, 1024, 512, 128, 1, nullptr);
  gemm_k<1, 2, true, 1><<<dim3(8, 8, 8), blk, 0, stream>>>(
      Hh, nullptr, dw2Th, nullptr, dec_b2, nullptr, H2h, nullptr, 1024, 512, 512, 1, nullptr);
  gemm_loss_k<1><<<dim3(64, 8, 8), blk, 0, stream>>>(
      H2h, nullptr, dw3Th, nullptr, dec_b3, x, nullptr, nullptr, part, 512);
  loss_reduce_k<<<32, blk, 0, stream>>>(part, loss, nullptr);
  argmin_flag_k<<<4, blk, 0, stream>>>(loss, idx, out_ix, ambc, amb);

  // Re-resolve ambiguous samples with 3-pass split-bf16 (precise)
  gather_x_k<<<1024, blk, 0, stream>>>(x, ambc, amb, XgH, XgL);
  gemm_k<3, 2, true, 1><<<dim3(8, 8, 8), blk, 0, stream>>>(
      XgH, XgL, ew1Th, ew1Tl, enc_b1, nullptr, PAh, PAl, 1024, 512, 8192, 0, ambc);
  gemm_k<3, 2, true, 1><<<dim3(8, 8, 8), blk, 0, stream>>>(
      PAh, PAl, ew2Th, ew2Tl, enc_b2, nullptr, PBh, PBl, 1024, 512, 512, 1, ambc);
  gemm_k<3, 2, false, 0><<<dim3(4, 8, 8), blk, 0, stream>>>(
      PBh, PBl, mlvTh, mlvTl, mlvB, mlvP, nullptr, nullptr, 1024, 256, 512, 1, ambc);
  zP_k<<<4096, blk, 0, stream>>>(mlvP, eps, ambc, amb, ZgH, ZgL);
  gemm_k<3, 2, true, 1><<<dim3(8, 8, 8), blk, 0, stream>>>(
      ZgH, ZgL, dw1Th, dw1Tl, dec_b1, nullptr, PAh, PAl, 1024, 512, 128, 1, ambc);
  gemm_k<3, 2, true, 1><<<dim3(8, 8, 8), blk, 0, stream>>>(
      PAh, PAl, dw2Th, dw2Tl, dec_b2, nullptr, PBh, PBl, 1024, 512, 512, 1, ambc);
  gemm_loss_k<3><<<dim3(64, 8, 8), blk, 0, stream>>>(
      PBh, PBl, dw3Th, dw3Tl, dec_b3, x, amb, ambc, part, 512);
  loss_reduce_k<<<32, blk, 0, stream>>>(part, lossP, ambc);
  fix_idx_k<<<4, blk, 0, stream>>>(lossP, ambc, amb, idx, out_ix);

  // Outputs
  select_k<<<512, blk, 0, stream>>>(mlv, idx, out_mu, out_lv);
  compact_k<<<1, 1024, 0, stream>>>(idx, counts, lists);
  gather_out_k<<<dim3(64, 8, 8), blk, 0, stream>>>(
      H2h, dw3Th, dec_b3, counts, lists, out_xh, 8192, 512);
}